// Round 9
// baseline (1301.112 us; speedup 1.0000x reference)
//
#include <hip/hip_runtime.h>

constexpr int H    = 128;
constexpr int LNUM = 5;
constexpr int NG   = 512;
constexpr int EMB  = 640;   // LNUM * H
constexpr float BN_EPS = 1e-5f;

typedef __attribute__((ext_vector_type(8))) short bf16x8;
typedef __attribute__((ext_vector_type(4))) float f32x4;

__device__ inline unsigned short f2bf(float f){
  unsigned u = __builtin_bit_cast(unsigned, f);
  u += 0x7FFF + ((u >> 16) & 1);
  return (unsigned short)(u >> 16);
}
__device__ inline float bf2f(unsigned short h){
  unsigned u = ((unsigned)h) << 16;
  return __builtin_bit_cast(float, u);
}

// bijective XCD chunk swizzle (m204)
__device__ inline int xcd_swz(int bid, int nwg){
  int q = nwg >> 3, r = nwg & 7;
  int xcd = bid & 7, idx = bid >> 3;
  return (xcd < r ? xcd*(q+1) : r*(q+1) + (xcd-r)*q) + idx;
}

// ---------------- utility ----------------
__global__ void k_zerof(float* p, int n){
  int i = blockIdx.x*256 + threadIdx.x;
  if (i < n) p[i] = 0.f;
}
__global__ void k_zeroi(int* p, int n){
  int i = blockIdx.x*256 + threadIdx.x;
  if (i < n) p[i] = 0;
}

// ---------------- CSR build ----------------
__global__ void k_hist(const int* __restrict__ dst, int E, int* deg){
  int e = blockIdx.x*256 + threadIdx.x;
  if (e < E) atomicAdd(&deg[dst[e]], 1);
}

__global__ __launch_bounds__(1024) void k_scan(int* degcur, int* __restrict__ rowptr, int n){
  __shared__ int wsum[16];
  __shared__ int carry;
  int tid = threadIdx.x, wid = tid >> 6, lane = tid & 63;
  if (tid == 0){ carry = 0; rowptr[0] = 0; }
  __syncthreads();
  for (int base = 0; base < n; base += 1024){
    int v = (base + tid < n) ? degcur[base + tid] : 0;
    int s = v;
#pragma unroll
    for (int off = 1; off < 64; off <<= 1){
      int t = __shfl_up(s, off);
      if (lane >= off) s += t;
    }
    if (lane == 63) wsum[wid] = s;
    __syncthreads();
    if (wid == 0 && lane < 16){
      int wv = wsum[lane];
#pragma unroll
      for (int off = 1; off < 16; off <<= 1){
        int t = __shfl_up(wv, off);
        if (lane >= off) wv += t;
      }
      wsum[lane] = wv;
    }
    __syncthreads();
    int incl = s + (wid ? wsum[wid-1] : 0) + carry;
    if (base + tid < n){ rowptr[base + tid + 1] = incl; degcur[base + tid] = incl - v; }
    __syncthreads();
    if (tid == 0) carry += wsum[15];
    __syncthreads();
  }
}

__global__ void k_scatter(const int* __restrict__ src, const int* __restrict__ dst,
                          int E, int* cursor, int* __restrict__ colsrc){
  int e = blockIdx.x*256 + threadIdx.x;
  if (e < E){
    int d = dst[e];
    int pos = atomicAdd(&cursor[d], 1);
    colsrc[pos] = src[e];
  }
}

__global__ void k_gstart(const int* __restrict__ batch, int N, int* __restrict__ gstart){
  int g = blockIdx.x*256 + threadIdx.x;
  if (g <= NG){
    int lo = 0, hi = N;
    while (lo < hi){
      int mid = (lo + hi) >> 1;
      if (batch[mid] < g) lo = mid + 1; else hi = mid;
    }
    gstart[g] = lo;
  }
}

// ---- weight cast+transpose: W[k][n] f32 -> Wt[n][ldt] bf16 at column offset koff ----
__global__ void k_castT(const float* __restrict__ W, unsigned short* __restrict__ Wt,
                        int K, int Nn, int ldt, int koff){
  __shared__ float sh[32][33];
  const size_t in_off  = (size_t)blockIdx.z * K * Nn;
  const size_t out_off = (size_t)blockIdx.z * Nn * ldt;
  int n0 = blockIdx.x*32, k0 = blockIdx.y*32;
  int tx = threadIdx.x, ty = threadIdx.y;   // 32 x 8
  for (int r = ty; r < 32; r += 8)
    sh[r][tx] = W[in_off + (size_t)(k0 + r)*Nn + n0 + tx];
  __syncthreads();
  for (int r = ty; r < 32; r += 8)
    Wt[out_off + (size_t)(n0 + r)*ldt + koff + k0 + tx] = f2bf(sh[tx][r]);
}

__global__ void k_bias2(const float* __restrict__ a, const float* __restrict__ b,
                        float* __restrict__ o){
  int i = threadIdx.x;
  o[i] = a[i] + b[i];
}

// ---------------- pooling + prediction heads ----------------
__global__ __launch_bounds__(320) void k_pool(const unsigned short* __restrict__ xall,
                                              const int* __restrict__ gstart,
                                              float* __restrict__ pooled){
  int g = blockIdx.x;
  int t = threadIdx.x;
  int n0 = gstart[g], n1 = gstart[g+1];
  float a0 = 0.f, a1 = 0.f;
  for (int n = n0; n < n1; ++n){
    unsigned u = ((const unsigned*)xall)[(size_t)n*(EMB/2) + t];
    a0 += bf2f((unsigned short)u); a1 += bf2f((unsigned short)(u >> 16));
  }
  *(float2*)(pooled + (size_t)g*EMB + 2*t) = make_float2(a0, a1);
}

__global__ __launch_bounds__(128) void k_pred(const float* __restrict__ pooled,
                                              const float* __restrict__ W,
                                              const float* __restrict__ b,
                                              float* __restrict__ xcat){
  int g = blockIdx.x, l = blockIdx.y, o = threadIdx.x;
  __shared__ float sh[128];
  sh[o] = pooled[(size_t)g*EMB + l*H + o];
  __syncthreads();
  const float* Wl = W + (size_t)l*H*H;
  float acc = b[l*H + o];
  for (int k = 0; k < H; ++k) acc = fmaf(sh[k], Wl[k*H + o], acc);
  xcat[(size_t)g*EMB + l*H + o] = acc;
}

// ---- bf16 MFMA GEMM, 256x128 tile, BK=64, 8 waves (4Mx2N, 64x64/wave) ----
// m201-style 4-phase schedule per K-tile, 3 LDS buffers, counted vmcnt(6).
// DUAL: A rows are [A | A2] concatenated along K (each K/2 wide).
template<bool RELU, bool OUT_BF16, bool DUAL>
__global__ __launch_bounds__(512) void k_mm(
    const unsigned short* __restrict__ A, int lda,
    const unsigned short* __restrict__ A2,
    const unsigned short* __restrict__ Bt, int ldb,
    const float* __restrict__ bias,
    void* __restrict__ Cv, int ldc,
    int M, int K)
{
  __shared__ union LdsU {
    unsigned short stage[3][24576];   // per buf: A bytes [0,32K), B [32K,48K)
    unsigned short sc16[256*136];     // epilogue scratch bf16 (69.6 KB)
    float          sc32[128*132];     // epilogue scratch f32 half-tile (66 KB)
  } u;
  const int tid  = threadIdx.x;
  const int lane = tid & 63;
  const int w    = tid >> 6;            // 0..7
  const int wrr  = w >> 1;              // 0..3 row-wave
  const int wcc  = w & 1;               // 0..1 col-wave

  const int nwg = gridDim.x * gridDim.y;
  const int bid = blockIdx.y * gridDim.x + blockIdx.x;
  const int wg  = xcd_swz(bid, nwg);
  const int col0 = (wg % gridDim.x) * 128;
  const int row0 = (wg / gridDim.x) * 256;
  const int KA   = DUAL ? (K >> 1) : K;

  // staging sources: wave w owns 4 KB of A (4 chunks) + 2 KB of B (2 chunks)
  const unsigned short *sA[4], *sA2p[4], *sB[2];
  int dA[4], dB[2];
#pragma unroll
  for (int j = 0; j < 4; ++j){
    int d = w*4096 + j*1024 + lane*16;        // byte in 32 KB A region
    int m = d >> 7;                           // tile row 0..255 (128-B rows)
    int inner = (d & 127) ^ ((m & 7) << 4);   // inverse swizzle
    int gm = row0 + m; if (gm > M-1) gm = M-1;
    sA[j] = A + (size_t)gm*lda + (inner >> 1);
    if (DUAL) sA2p[j] = A2 + (size_t)gm*lda + (inner >> 1);
    dA[j] = w*4096 + j*1024;
  }
#pragma unroll
  for (int j = 0; j < 2; ++j){
    int d = w*2048 + j*1024 + lane*16;        // byte in 16 KB B region
    int m = d >> 7;                           // 0..127
    int inner = (d & 127) ^ ((m & 7) << 4);
    sB[j] = Bt + (size_t)(col0 + m)*ldb + (inner >> 1);
    dB[j] = 32768 + w*2048 + j*1024;
  }

  f32x4 acc[4][4];                            // [ib(row-frag)][j(col-frag)]
#pragma unroll
  for (int i = 0; i < 4; ++i)
#pragma unroll
    for (int j = 0; j < 4; ++j)
      acc[i][j] = (f32x4){0.f, 0.f, 0.f, 0.f};

  auto STAGE_A = [&](int buf, int kt, int j0){   // 2 loads
    int k0 = kt*64, ka = k0;
    bool sec = DUAL && (k0 >= KA);
    if (sec) ka = k0 - KA;
    char* base = (char*)&u.stage[buf][0];
#pragma unroll
    for (int jj = 0; jj < 2; ++jj){
      const unsigned short* s = sec ? (sA2p[j0+jj] + ka) : (sA[j0+jj] + ka);
      __builtin_amdgcn_global_load_lds(
          (const __attribute__((address_space(1))) void*)s,
          (__attribute__((address_space(3))) void*)(base + dA[j0+jj]), 16, 0, 0);
    }
  };
  auto STAGE_B = [&](int buf, int kt){           // 2 loads
    int k0 = kt*64;
    char* base = (char*)&u.stage[buf][0];
#pragma unroll
    for (int jj = 0; jj < 2; ++jj)
      __builtin_amdgcn_global_load_lds(
          (const __attribute__((address_space(1))) void*)(sB[jj] + k0),
          (__attribute__((address_space(3))) void*)(base + dB[jj]), 16, 0, 0);
  };

  const int NT = K / 64;        // 10 or 20 here (>= 3)
  STAGE_A(0, 0, 0); STAGE_A(0, 0, 2); STAGE_B(0, 0);
  STAGE_A(1, 1, 0); STAGE_A(1, 1, 2); STAGE_B(1, 1);
  asm volatile("s_waitcnt vmcnt(6)" ::: "memory");   // tile 0 landed, tile 1 flying
  __syncthreads();

  for (int t = 0; t < NT; ++t){
    const char* Ab = (const char*)&u.stage[t % 3][0];
    const char* Bb = Ab + 32768;
    const int kbq = (lane >> 4) << 4;
    const bool pre = (t + 2 < NT);
    const int bufn = (t + 2) % 3;
    bf16x8 bfr[4][2];
#pragma unroll
    for (int ib = 0; ib < 4; ++ib){
      // ---- phase ib: ds-load one A frag-pair (+all B in phase 0), issue 2 stage loads
      bf16x8 af0, af1;
      {
        int row = wrr*64 + ib*16 + (lane & 15);
        af0 = *(const bf16x8*)(Ab + ((row*128 + kbq)      ^ ((row & 7) << 4)));
        af1 = *(const bf16x8*)(Ab + ((row*128 + 64 + kbq) ^ ((row & 7) << 4)));
      }
      if (ib == 0){
#pragma unroll
        for (int j = 0; j < 4; ++j){
          int col = wcc*64 + j*16 + (lane & 15);
          bfr[j][0] = *(const bf16x8*)(Bb + ((col*128 + kbq)      ^ ((col & 7) << 4)));
          bfr[j][1] = *(const bf16x8*)(Bb + ((col*128 + 64 + kbq) ^ ((col & 7) << 4)));
        }
      }
      if (pre){
        if (ib == 0) STAGE_A(bufn, t + 2, 0);
        else if (ib == 1) STAGE_A(bufn, t + 2, 2);
        else if (ib == 2) STAGE_B(bufn, t + 2);
      }
      __syncthreads();
      asm volatile("s_waitcnt lgkmcnt(0)" ::: "memory");
      __builtin_amdgcn_sched_barrier(0);
      __builtin_amdgcn_s_setprio(1);
#pragma unroll
      for (int j = 0; j < 4; ++j){
        acc[ib][j] = __builtin_amdgcn_mfma_f32_16x16x32_bf16(af0, bfr[j][0], acc[ib][j], 0, 0, 0);
        acc[ib][j] = __builtin_amdgcn_mfma_f32_16x16x32_bf16(af1, bfr[j][1], acc[ib][j], 0, 0, 0);
      }
      __builtin_amdgcn_s_setprio(0);
      __builtin_amdgcn_sched_barrier(0);
      __syncthreads();
    }
    // ---- end of K-tile: make tile t+1 readable (counted, never 0 until tail)
    if (t + 1 < NT){
      if (t + 2 < NT) asm volatile("s_waitcnt vmcnt(6)" ::: "memory");
      else            asm volatile("s_waitcnt vmcnt(0)" ::: "memory");
      __syncthreads();
    }
  }

  // ---- epilogue: transpose via LDS, coalesced stream-out ----
  __syncthreads();   // staging buffers now dead
  if (OUT_BF16){
#pragma unroll
    for (int j = 0; j < 4; ++j){
      int cl = wcc*64 + j*16 + (lane & 15);
      float bs = bias[col0 + cl];
#pragma unroll
      for (int ib = 0; ib < 4; ++ib){
        int rb = wrr*64 + ib*16 + ((lane >> 4) << 2);
#pragma unroll
        for (int r = 0; r < 4; ++r){
          float v = acc[ib][j][r] + bs;
          if (RELU) v = fmaxf(v, 0.f);
          u.sc16[(rb + r)*136 + cl] = f2bf(v);
        }
      }
    }
    __syncthreads();
    unsigned short* Cb = (unsigned short*)Cv;
    for (int idx = tid; idx < 256*16; idx += 512){
      int rr = idx >> 4, seg = idx & 15;
      int grow = row0 + rr;
      if (grow < M){
        uint4 vv = *(const uint4*)&u.sc16[rr*136 + seg*8];
        *(uint4*)(Cb + (size_t)grow*ldc + col0 + seg*8) = vv;
      }
    }
  } else {
    float* Cf = (float*)Cv;
#pragma unroll
    for (int p = 0; p < 2; ++p){      // half-tile passes (scratch is 128 rows)
      if ((wrr >> 1) == p){
#pragma unroll
        for (int j = 0; j < 4; ++j){
          int cl = wcc*64 + j*16 + (lane & 15);
          float bs = bias[col0 + cl];
#pragma unroll
          for (int ib = 0; ib < 4; ++ib){
            int lr = (wrr & 1)*64 + ib*16 + ((lane >> 4) << 2);
#pragma unroll
            for (int r = 0; r < 4; ++r){
              float v = acc[ib][j][r] + bs;
              if (RELU) v = fmaxf(v, 0.f);
              u.sc32[(lr + r)*132 + cl] = v;
            }
          }
        }
      }
      __syncthreads();
      for (int idx = tid; idx < 128*32; idx += 512){
        int rr = idx >> 5, seg = idx & 31;
        int grow = row0 + p*128 + rr;
        if (grow < M){
          float4 vv = *(const float4*)&u.sc32[rr*132 + seg*4];
          *(float4*)(Cf + (size_t)grow*ldc + col0 + seg*4) = vv;
        }
      }
      __syncthreads();
    }
  }
}

// ------- fused GIN-aggregate + conv GEMM1 + stats: ub = agg(h) @ W1 + b1 -------
template<bool IN_BF16>
__global__ __launch_bounds__(512) void k_mmca(
    const void* __restrict__ hin, int ldh,
    const int* __restrict__ rowptr, const int* __restrict__ colsrc,
    const float* __restrict__ epsp,
    const unsigned short* __restrict__ Bt,    // [128][128] bf16, n-major
    const float* __restrict__ bias,
    unsigned short* __restrict__ C, int ldc,
    float* __restrict__ sums, float* __restrict__ sumsq,
    int M)
{
  __shared__ unsigned short shm[2*128*128];   // As | Bs (32 KB each); epilogue reuse
  unsigned short* As = shm;
  unsigned short* Bs = shm + 16384;
  const int tid  = threadIdx.x;
  const int lane = tid & 63;
  const int w    = tid >> 6;
  const int wr   = w >> 2, wc = w & 3;

  const int wg   = xcd_swz(blockIdx.x, gridDim.x);
  const int row0 = wg * 128;

  // issue B staging first (pre-swizzled source, linear dest)
#pragma unroll
  for (int j = 0; j < 4; ++j){
    int d = w*4096 + j*1024 + lane*16;
    int m = d >> 8;
    int inner = (d & 255) ^ ((m & 15) << 4);
    __builtin_amdgcn_global_load_lds(
        (const __attribute__((address_space(1))) void*)(Bt + (size_t)m*H + (inner >> 1)),
        (__attribute__((address_space(3))) void*)((char*)Bs + w*4096 + j*1024),
        16, 0, 0);
  }

  // gather A: thread handles row r = tid>>2, 32 cols at c0 = (tid&3)*32
  {
    int r  = tid >> 2;
    int c0 = (tid & 3) << 5;
    int node = row0 + r; if (node > M-1) node = M-1;
    float ep = 1.0f + *epsp;
    float a[32];
    if (IN_BF16){
      const unsigned short* src = (const unsigned short*)hin + (size_t)node*ldh + c0;
#pragma unroll
      for (int q = 0; q < 4; ++q){
        uint2 v = *(const uint2*)(src + q*8);
        a[q*8+0] = ep*bf2f((unsigned short)v.x);  a[q*8+1] = ep*bf2f((unsigned short)(v.x>>16));
        uint2 v2 = *(const uint2*)(src + q*8 + 4);
        a[q*8+2] = ep*bf2f((unsigned short)v.y);  a[q*8+3] = ep*bf2f((unsigned short)(v.y>>16));
        a[q*8+4] = ep*bf2f((unsigned short)v2.x); a[q*8+5] = ep*bf2f((unsigned short)(v2.x>>16));
        a[q*8+6] = ep*bf2f((unsigned short)v2.y); a[q*8+7] = ep*bf2f((unsigned short)(v2.y>>16));
      }
    } else {
      const float* src = (const float*)hin + (size_t)node*ldh + c0;
#pragma unroll
      for (int q = 0; q < 32; q += 4){
        float4 f = *(const float4*)(src + q);
        a[q] = ep*f.x; a[q+1] = ep*f.y; a[q+2] = ep*f.z; a[q+3] = ep*f.w;
      }
    }
    int e = rowptr[node], e1 = rowptr[node+1];
    for (; e < e1; ++e){
      int s = colsrc[e];
      if (IN_BF16){
        const unsigned short* p = (const unsigned short*)hin + (size_t)s*ldh + c0;
        uint4 v0 = *(const uint4*)(p);
        uint4 v1 = *(const uint4*)(p + 8);
        uint4 v2 = *(const uint4*)(p + 16);
        uint4 v3 = *(const uint4*)(p + 24);
        const unsigned* uu[4] = {(const unsigned*)&v0, (const unsigned*)&v1,
                                 (const unsigned*)&v2, (const unsigned*)&v3};
#pragma unroll
        for (int q = 0; q < 4; ++q)
#pragma unroll
          for (int k = 0; k < 4; ++k){
            unsigned x = uu[q][k];
            a[q*8 + 2*k]     += bf2f((unsigned short)x);
            a[q*8 + 2*k + 1] += bf2f((unsigned short)(x >> 16));
          }
      } else {
        const float* p = (const float*)hin + (size_t)s*ldh + c0;
#pragma unroll
        for (int q = 0; q < 32; q += 4){
          float4 f = *(const float4*)(p + q);
          a[q] += f.x; a[q+1] += f.y; a[q+2] += f.z; a[q+3] += f.w;
        }
      }
    }
    // write 32 bf16 (64 B = 4 swizzled 16-B chunks) into As
#pragma unroll
    for (int q = 0; q < 4; ++q){
      unsigned pk[4];
#pragma unroll
      for (int k = 0; k < 4; ++k)
        pk[k] = (unsigned)f2bf(a[q*8 + 2*k]) | ((unsigned)f2bf(a[q*8 + 2*k + 1]) << 16);
      int byte = (r*256 + (tid & 3)*64 + q*16) ^ ((r & 15) << 4);
      *(uint4*)((char*)As + byte) = *(uint4*)pk;
    }
  }

  asm volatile("s_waitcnt vmcnt(0)" ::: "memory");
  __syncthreads();

  f32x4 acc[4][2];
#pragma unroll
  for (int i = 0; i < 4; ++i)
#pragma unroll
    for (int j = 0; j < 2; ++j)
      acc[i][j] = (f32x4){0.f, 0.f, 0.f, 0.f};

#pragma unroll
  for (int kk = 0; kk < 4; ++kk){
    const int kb = kk*64 + ((lane >> 4) << 4);
    bf16x8 af[4], bfr[2];
#pragma unroll
    for (int i = 0; i < 4; ++i){
      int row = wr*64 + i*16 + (lane & 15);
      af[i] = *(const bf16x8*)((const char*)As + ((row*256 + kb) ^ ((row & 15) << 4)));
    }
#pragma unroll
    for (int j = 0; j < 2; ++j){
      int col = wc*32 + j*16 + (lane & 15);
      bfr[j] = *(const bf16x8*)((const char*)Bs + ((col*256 + kb) ^ ((col & 15) << 4)));
    }
#pragma unroll
    for (int i = 0; i < 4; ++i)
#pragma unroll
      for (int j = 0; j < 2; ++j)
        acc[i][j] = __builtin_amdgcn_mfma_f32_16x16x32_bf16(af[i], bfr[j], acc[i][j], 0, 0, 0);
  }

  // fused column stats
#pragma unroll
  for (int j = 0; j < 2; ++j){
    int col = wc*32 + j*16 + (lane & 15);
    float bs = bias[col];
    float s = 0.f, q = 0.f;
#pragma unroll
    for (int i = 0; i < 4; ++i){
      int rb = row0 + wr*64 + i*16 + ((lane >> 4) << 2);
#pragma unroll
      for (int r = 0; r < 4; ++r){
        if (rb + r < M){
          float v = acc[i][j][r] + bs;
          s += v; q += v*v;
        }
      }
    }
    s += __shfl_xor(s, 16); q += __shfl_xor(q, 16);
    s += __shfl_xor(s, 32); q += __shfl_xor(q, 32);
    if (lane < 16){
      atomicAdd(&sums[col], s);
      atomicAdd(&sumsq[col], q);
    }
  }

  // epilogue: transpose via LDS (staging dead), coalesced 16-B stores
  __syncthreads();
#pragma unroll
  for (int j = 0; j < 2; ++j){
    int cl = wc*32 + j*16 + (lane & 15);
    float bs = bias[cl];
#pragma unroll
    for (int i = 0; i < 4; ++i){
      int rb = wr*64 + i*16 + ((lane >> 4) << 2);
#pragma unroll
      for (int r = 0; r < 4; ++r)
        shm[(rb + r)*136 + cl] = f2bf(acc[i][j][r] + bs);
    }
  }
  __syncthreads();
  for (int idx = tid; idx < 128*16; idx += 512){
    int rr = idx >> 4, seg = idx & 15;
    int grow = row0 + rr;
    if (grow < M){
      uint4 vv = *(const uint4*)&shm[rr*136 + seg*8];
      *(uint4*)(C + (size_t)grow*ldc + seg*8) = vv;
    }
  }
}

// ------- conv GEMM2 with inline BN1 finalize on A + stats: tb = relu(bn1(ub)) @ W2 + b2 -------
__global__ __launch_bounds__(512) void k_mmc2(
    const unsigned short* __restrict__ A,     // [M][128] bf16 (pre-BN1)
    const unsigned short* __restrict__ Bt,    // [128][128] bf16, n-major
    const float* __restrict__ bias,           // [128]
    const float* __restrict__ statin,         // BN1 slot: sums[128]|sumsq[128]
    const float* __restrict__ g1, const float* __restrict__ be1,
    float invn,
    unsigned short* __restrict__ C, int ldc,
    float* __restrict__ sums, float* __restrict__ sumsq,   // BN2 slot
    int M)
{
  __shared__ unsigned short shm[2*128*128];
  __shared__ float bnsc[128], bnsf[128];
  unsigned short* As = shm;
  unsigned short* Bs = shm + 16384;
  const int tid  = threadIdx.x;
  const int lane = tid & 63;
  const int w    = tid >> 6;
  const int wr   = w >> 2, wc = w & 3;

  const int wg   = xcd_swz(blockIdx.x, gridDim.x);
  const int row0 = wg * 128;

#pragma unroll
  for (int j = 0; j < 4; ++j){
    int d = w*4096 + j*1024 + lane*16;
    int m = d >> 8;
    int inner = (d & 255) ^ ((m & 15) << 4);
    int gm = row0 + m; if (gm > M-1) gm = M-1;
    __builtin_amdgcn_global_load_lds(
        (const __attribute__((address_space(1))) void*)(A + (size_t)gm*H + (inner >> 1)),
        (__attribute__((address_space(3))) void*)((char*)As + w*4096 + j*1024),
        16, 0, 0);
    __builtin_amdgcn_global_load_lds(
        (const __attribute__((address_space(1))) void*)(Bt + (size_t)m*H + (inner >> 1)),
        (__attribute__((address_space(3))) void*)((char*)Bs + w*4096 + j*1024),
        16, 0, 0);
  }

  // inline BN1 finalize (overlaps with staging)
  if (tid < 128){
    float m = statin[tid]*invn;
    float v = statin[128 + tid]*invn - m*m;
    float inv = rsqrtf(v + BN_EPS);
    float sc = g1[tid]*inv;
    bnsc[tid] = sc;
    bnsf[tid] = be1[tid] - m*sc;
  }

  asm volatile("s_waitcnt vmcnt(0)" ::: "memory");
  __syncthreads();

  f32x4 acc[4][2];
#pragma unroll
  for (int i = 0; i < 4; ++i)
#pragma unroll
    for (int j = 0; j < 2; ++j)
      acc[i][j] = (f32x4){0.f, 0.f, 0.f, 0.f};

#pragma unroll
  for (int kk = 0; kk < 4; ++kk){
    const int kb = kk*64 + ((lane >> 4) << 4);
    bf16x8 af[4], bfr[2];
#pragma unroll
    for (int i = 0; i < 4; ++i){
      int row = wr*64 + i*16 + (lane & 15);
      af[i] = *(const bf16x8*)((const char*)As + ((row*256 + kb) ^ ((row & 15) << 4)));
    }
#pragma unroll
    for (int j = 0; j < 2; ++j){
      int col = wc*32 + j*16 + (lane & 15);
      bfr[j] = *(const bf16x8*)((const char*)Bs + ((col*256 + kb) ^ ((col & 15) << 4)));
    }
    {
      int k8 = kk*32 + ((lane >> 4) << 3);
      float4 s0 = *(const float4*)(&bnsc[k8]), s1 = *(const float4*)(&bnsc[k8 + 4]);
      float4 f0 = *(const float4*)(&bnsf[k8]), f1 = *(const float4*)(&bnsf[k8 + 4]);
      float sc[8] = {s0.x,s0.y,s0.z,s0.w,s1.x,s1.y,s1.z,s1.w};
      float sf[8] = {f0.x,f0.y,f0.z,f0.w,f1.x,f1.y,f1.z,f1.w};
#pragma unroll
      for (int i = 0; i < 4; ++i){
        bf16x8 aa = af[i], o;
#pragma unroll
        for (int jj = 0; jj < 8; ++jj){
          float v = fmaxf(fmaf(sc[jj], bf2f((unsigned short)aa[jj]), sf[jj]), 0.f);
          o[jj] = (short)f2bf(v);
        }
        af[i] = o;
      }
    }
#pragma unroll
    for (int i = 0; i < 4; ++i)
#pragma unroll
      for (int j = 0; j < 2; ++j)
        acc[i][j] = __builtin_amdgcn_mfma_f32_16x16x32_bf16(af[i], bfr[j], acc[i][j], 0, 0, 0);
  }

#pragma unroll
  for (int j = 0; j < 2; ++j){
    int col = wc*32 + j*16 + (lane & 15);
    float bs = bias[col];
    float s = 0.f, q = 0.f;
#pragma unroll
    for (int i = 0; i < 4; ++i){
      int rb = row0 + wr*64 + i*16 + ((lane >> 4) << 2);
#pragma unroll
      for (int r = 0; r < 4; ++r){
        if (rb + r < M){
          float v = acc[i][j][r] + bs;
          s += v; q += v*v;
        }
      }
    }
    s += __shfl_xor(s, 16); q += __shfl_xor(q, 16);
    s += __shfl_xor(s, 32); q += __shfl_xor(q, 32);
    if (lane < 16){
      atomicAdd(&sums[col], s);
      atomicAdd(&sumsq[col], q);
    }
  }

  __syncthreads();
#pragma unroll
  for (int j = 0; j < 2; ++j){
    int cl = wc*32 + j*16 + (lane & 15);
    float bs = bias[cl];
#pragma unroll
    for (int i = 0; i < 4; ++i){
      int rb = wr*64 + i*16 + ((lane >> 4) << 2);
#pragma unroll
      for (int r = 0; r < 4; ++r)
        shm[(rb + r)*136 + cl] = f2bf(acc[i][j][r] + bs);
    }
  }
  __syncthreads();
  for (int idx = tid; idx < 128*16; idx += 512){
    int rr = idx >> 4, seg = idx & 15;
    int grow = row0 + rr;
    if (grow < M){
      uint4 vv = *(const uint4*)&shm[rr*136 + seg*8];
      *(uint4*)(C + (size_t)grow*ldc + seg*8) = vv;
    }
  }
}

// ---- BN2 apply with inline finalize: out = bf16(relu(sc*U+sf)) ----
__global__ __launch_bounds__(256) void k_bnapply(const unsigned short* __restrict__ U,
                                                 const float* __restrict__ statp,
                                                 const float* __restrict__ g,
                                                 const float* __restrict__ b,
                                                 float invn,
                                                 unsigned short* __restrict__ out,
                                                 int ldo, int n){
  int i = blockIdx.x*256 + threadIdx.x;
  int total = n * (H/4);
  if (i < total){
    int r = i >> 5;
    int c4 = (i & 31) << 2;
    float4 sm = *(const float4*)(statp + c4);
    float4 sq = *(const float4*)(statp + 128 + c4);
    float4 gg = *(const float4*)(g + c4);
    float4 bb = *(const float4*)(b + c4);
    float m0 = sm.x*invn, m1 = sm.y*invn, m2 = sm.z*invn, m3 = sm.w*invn;
    float s0 = gg.x*rsqrtf(sq.x*invn - m0*m0 + BN_EPS);
    float s1 = gg.y*rsqrtf(sq.y*invn - m1*m1 + BN_EPS);
    float s2 = gg.z*rsqrtf(sq.z*invn - m2*m2 + BN_EPS);
    float s3 = gg.w*rsqrtf(sq.w*invn - m3*m3 + BN_EPS);
    float f0 = bb.x - m0*s0, f1 = bb.y - m1*s1, f2 = bb.z - m2*s2, f3 = bb.w - m3*s3;
    uint2 up = *(const uint2*)(U + (size_t)r*H + c4);
    float a = fmaxf(fmaf(s0, bf2f((unsigned short)up.x),       f0), 0.f);
    float c = fmaxf(fmaf(s1, bf2f((unsigned short)(up.x>>16)), f1), 0.f);
    float d = fmaxf(fmaf(s2, bf2f((unsigned short)up.y),       f2), 0.f);
    float e = fmaxf(fmaf(s3, bf2f((unsigned short)(up.y>>16)), f3), 0.f);
    uint2 o;
    o.x = (unsigned)f2bf(a) | ((unsigned)f2bf(c) << 16);
    o.y = (unsigned)f2bf(d) | ((unsigned)f2bf(e) << 16);
    *(uint2*)(out + (size_t)r*ldo + c4) = o;
  }
}

// ---------------- f32 GEMM 64x64 (graph FF, M=512) ----------------
template<bool RELU, bool ADD_D>
__global__ __launch_bounds__(256) void k_gemm64(
    const float* __restrict__ A, int lda,
    const float* __restrict__ B, int ldb,
    const float* __restrict__ bias,
    const float* D, int ldd,
    float* C, int ldc,
    int M, int N, int K)
{
  __shared__ float As[32][68];
  __shared__ float Bs[32][64];
  const int tid  = threadIdx.x;
  const int tx   = tid & 15;
  const int ty   = tid >> 4;
  const int row0 = blockIdx.x * 64;
  const int col0 = blockIdx.y * 64;
  const int am = tid >> 3;
  const int ak = (tid & 7) << 2;
  const int bk = tid >> 4;
  const int bn = (tid & 15) << 2;
  float acc[4][4] = {};

  for (int k0 = 0; k0 < K; k0 += 32){
#pragma unroll
    for (int h = 0; h < 2; ++h){
      int m  = am + h*32;
      int gr = row0 + m;
      float4 v = make_float4(0.f, 0.f, 0.f, 0.f);
      if (gr < M) v = *(const float4*)(A + (size_t)gr*lda + k0 + ak);
      As[ak+0][m]=v.x; As[ak+1][m]=v.y; As[ak+2][m]=v.z; As[ak+3][m]=v.w;
    }
#pragma unroll
    for (int h = 0; h < 2; ++h){
      int kk = bk + h*16;
      *(float4*)(&Bs[kk][bn]) = *(const float4*)(B + (size_t)(k0+kk)*ldb + col0 + bn);
    }
    __syncthreads();
#pragma unroll 8
    for (int k = 0; k < 32; ++k){
      float4 a = *(const float4*)(&As[k][ty<<2]);
      float4 b = *(const float4*)(&Bs[k][tx<<2]);
      float av[4] = {a.x,a.y,a.z,a.w};
      float bv[4] = {b.x,b.y,b.z,b.w};
#pragma unroll
      for (int i = 0; i < 4; ++i)
#pragma unroll
        for (int j = 0; j < 4; ++j)
          acc[i][j] = fmaf(av[i], bv[j], acc[i][j]);
    }
    __syncthreads();
  }

  const int col = col0 + (tx<<2);
  float4 bv = *(const float4*)(bias + col);
#pragma unroll
  for (int i = 0; i < 4; ++i){
    int row = row0 + (ty<<2) + i;
    if (row < M){
      float r[4] = {acc[i][0]+bv.x, acc[i][1]+bv.y, acc[i][2]+bv.z, acc[i][3]+bv.w};
      if (RELU){
#pragma unroll
        for (int j = 0; j < 4; ++j) r[j] = fmaxf(r[j], 0.f);
      }
      if (ADD_D){
        float4 d = *(const float4*)(D + (size_t)row*ldd + col);
        r[0]+=d.x; r[1]+=d.y; r[2]+=d.z; r[3]+=d.w;
      }
      *(float4*)(C + (size_t)row*ldc + col) = make_float4(r[0],r[1],r[2],r[3]);
    }
  }
}

// ---------------- host ----------------
extern "C" void kernel_launch(void* const* d_in, const int* in_sizes, int n_in,
                              void* d_out, int out_size, void* d_ws, size_t ws_size,
                              hipStream_t stream) {
  const float* x        = (const float*)d_in[0];
  const int*   ei       = (const int*)d_in[1];
  const int*   batch    = (const int*)d_in[2];
  const float* conv_W1  = (const float*)d_in[3];
  const float* conv_b1  = (const float*)d_in[4];
  const float* conv_g1  = (const float*)d_in[5];
  const float* conv_be1 = (const float*)d_in[6];
  const float* conv_W2  = (const float*)d_in[7];
  const float* conv_b2  = (const float*)d_in[8];
  const float* epsv     = (const float*)d_in[9];
  const float* bn_g     = (const float*)d_in[10];
  const float* bn_b     = (const float*)d_in[11];
  const float* pred_W   = (const float*)d_in[12];
  const float* pred_b   = (const float*)d_in[13];
  const float* gW       = (const float*)d_in[14];
  const float* gb       = (const float*)d_in[15];
  const float* gsW      = (const float*)d_in[16];
  const float* gsb      = (const float*)d_in[17];
  const float* lW       = (const float*)d_in[18];
  const float* lb       = (const float*)d_in[19];
  const float* lsW      = (const float*)d_in[20];
  const float* lsb      = (const float*)d_in[21];

  const int N = in_sizes[0] / H;
  const int E = in_sizes[1] / 2;
  const int* srcI = ei;
  const int* dstI = ei + E;

  float* out = (float*)d_out;
  float* GE = out;                              // [NG][EMB]
  float* NE = out + (size_t)NG*EMB;             // [N][EMB] f32
  float* XC = NE + (size_t)N*EMB;               // [NG][EMB]

  // ---- workspace layout ----
  unsigned short* xall = (unsigned short*)d_ws;             // [N][EMB] bf16
  unsigned short* h1   = xall + (size_t)N*EMB;              // [N][EMB] bf16
  unsigned short* h2   = h1 + (size_t)N*EMB;                // [N][EMB] bf16
  unsigned short* ub   = h1;                                // [N][H] (alias, conv loop)
  unsigned short* tb   = h1 + (size_t)N*H;                  // [N][H]

  float* pooled  = (float*)(h2 + (size_t)N*EMB);            // [NG][EMB]
  float* gtmp1   = pooled + (size_t)NG*EMB;
  float* gtmp2   = gtmp1 + (size_t)NG*EMB;
  float* slots   = gtmp2 + (size_t)NG*EMB;                  // [10][256] stat slots
  float* biasNE  = slots + 2560;                            // [640]
  unsigned short* W1t   = (unsigned short*)(biasNE + EMB);  // [L][H][H]
  unsigned short* W2t   = W1t + (size_t)LNUM*H*H;
  unsigned short* lWt01 = W2t + (size_t)LNUM*H*H;           // [2][EMB][EMB]
  unsigned short* Wcat  = lWt01 + (size_t)2*EMB*EMB;        // [EMB][2*EMB]
  int* rowptr = (int*)(Wcat + (size_t)2*EMB*EMB);           // [N+1]
  int* cursor = rowptr + (N + 1);                           // [N]
  int* colsrc = cursor + N;                                 // [E]
  int* gstart = colsrc + E;                                 // [NG+1]

  // stat slots must be zero every call
  k_zerof<<<10, 256, 0, stream>>>(slots, 2560);

  // CSR build
  k_zeroi<<<(N+255)/256, 256, 0, stream>>>(cursor, N);
  k_hist<<<(E+255)/256, 256, 0, stream>>>(dstI, E, cursor);
  k_scan<<<1, 1024, 0, stream>>>(cursor, rowptr, N);
  k_scatter<<<(E+255)/256, 256, 0, stream>>>(srcI, dstI, E, cursor, colsrc);
  k_gstart<<<(NG+256)/256, 256, 0, stream>>>(batch, N, gstart);

  // weights -> bf16 transposed [n][k]
  const dim3 tb32(32, 8);
  k_castT<<<dim3(H/32, H/32, LNUM), tb32, 0, stream>>>(conv_W1, W1t, H, H, H, 0);
  k_castT<<<dim3(H/32, H/32, LNUM), tb32, 0, stream>>>(conv_W2, W2t, H, H, H, 0);
  k_castT<<<dim3(EMB/32, EMB/32, 2), tb32, 0, stream>>>(lW, lWt01, EMB, EMB, EMB, 0);
  k_castT<<<dim3(EMB/32, EMB/32, 1), tb32, 0, stream>>>(lW + (size_t)2*EMB*EMB, Wcat,
                                                        EMB, EMB, 2*EMB, 0);
  k_castT<<<dim3(EMB/32, EMB/32, 1), tb32, 0, stream>>>(lsW, Wcat, EMB, EMB, 2*EMB, EMB);
  k_bias2<<<1, EMB, 0, stream>>>(lb + (size_t)2*EMB, lsb, biasNE);

  const float invn = 1.0f / (float)N;
  const int nrow = (N + 127)/128;               // 391

  for (int l = 0; l < LNUM; ++l){
    float* slot1 = slots + (size_t)l*512;       // BN1: sums|sumsq
    float* slot2 = slot1 + 256;                 // BN2

    // ub = agg(h) @ W1 + b1  (fused gather; bf16 out + stats)
    if (l == 0)
      k_mmca<false><<<nrow, 512, 0, stream>>>(
          x, H, rowptr, colsrc, epsv, W1t, conv_b1,
          ub, H, slot1, slot1 + 128, N);
    else
      k_mmca<true><<<nrow, 512, 0, stream>>>(
          xall + (size_t)(l-1)*H, EMB, rowptr, colsrc, epsv + l,
          W1t + (size_t)l*H*H, conv_b1 + l*H,
          ub, H, slot1, slot1 + 128, N);

    // tb = relu(bn1(ub)) @ W2 + b2  (inline BN1 finalize; bf16 out + stats)
    k_mmc2<<<nrow, 512, 0, stream>>>(
        ub, W2t + (size_t)l*H*H, conv_b2 + l*H,
        slot1, conv_g1 + l*H, conv_be1 + l*H, invn,
        tb, H, slot2, slot2 + 128, N);

    // xall[:,l*H:] = relu(bn2(tb))  (inline BN2 finalize)
    k_bnapply<<<(N*32 + 255)/256, 256, 0, stream>>>(
        tb, slot2, bn_g + l*H, bn_b + l*H, invn,
        xall + (size_t)l*H, EMB, N);
  }

  // pooling + per-layer prediction heads -> xcat
  k_pool<<<NG, 320, 0, stream>>>(xall, gstart, pooled);
  k_pred<<<dim3(NG, LNUM), 128, 0, stream>>>(pooled, pred_W, pred_b, XC);

  // graph FF (f32, M=512): GE = relu-chain(XC) + XC @ gsW + gsb
  const dim3 gg((NG + 63)/64, EMB/64);
  k_gemm64<false,false><<<gg, 256, 0, stream>>>(XC, EMB, gsW, EMB, gsb,
                                                nullptr, 0, GE, EMB, NG, EMB, EMB);
  k_gemm64<true,false><<<gg, 256, 0, stream>>>(XC, EMB, gW, EMB, gb,
                                               nullptr, 0, gtmp1, EMB, NG, EMB, EMB);
  k_gemm64<true,false><<<gg, 256, 0, stream>>>(gtmp1, EMB, gW + (size_t)EMB*EMB, EMB, gb + EMB,
                                               nullptr, 0, gtmp2, EMB, NG, EMB, EMB);
  k_gemm64<true,true><<<gg, 256, 0, stream>>>(gtmp2, EMB, gW + (size_t)2*EMB*EMB, EMB, gb + 2*EMB,
                                              GE, EMB, GE, EMB, NG, EMB, EMB);

  // node FF (bf16 MFMA, 256x128 tile, 8-phase-style schedule, XCD swizzle):
  const int nrow256 = (N + 255)/256;            // 196
  const dim3 gn(EMB/128, nrow256);              // (5, 196)
  // h1 = relu(xall @ lW0 + lb0)
  k_mm<true,true,false><<<gn, 512, 0, stream>>>(
      xall, EMB, nullptr, lWt01, EMB, lb, h1, EMB, N, EMB);
  // h2 = relu(h1 @ lW1 + lb1)
  k_mm<true,true,false><<<gn, 512, 0, stream>>>(
      h1, EMB, nullptr, lWt01 + (size_t)EMB*EMB, EMB, lb + EMB, h2, EMB, N, EMB);
  // NE = [h2 | xall] @ [lW2 ; lsW] + (lb2 + lsb)   (dual-A, K=1280, f32 out)
  k_mm<false,false,true><<<gn, 512, 0, stream>>>(
      h2, EMB, xall, Wcat, 2*EMB, biasNE, NE, EMB, N, 2*EMB);
}

// Round 10
// 1073.918 us; speedup vs baseline: 1.2116x; 1.2116x over previous
//
#include <hip/hip_runtime.h>

constexpr int H    = 128;
constexpr int LNUM = 5;
constexpr int NG   = 512;
constexpr int EMB  = 640;   // LNUM * H
constexpr float BN_EPS = 1e-5f;

typedef __attribute__((ext_vector_type(8))) short bf16x8;
typedef __attribute__((ext_vector_type(4))) float f32x4;

__device__ inline unsigned short f2bf(float f){
  unsigned u = __builtin_bit_cast(unsigned, f);
  u += 0x7FFF + ((u >> 16) & 1);
  return (unsigned short)(u >> 16);
}
__device__ inline float bf2f(unsigned short h){
  unsigned u = ((unsigned)h) << 16;
  return __builtin_bit_cast(float, u);
}

// bijective XCD chunk swizzle (m204)
__device__ inline int xcd_swz(int bid, int nwg){
  int q = nwg >> 3, r = nwg & 7;
  int xcd = bid & 7, idx = bid >> 3;
  return (xcd < r ? xcd*(q+1) : r*(q+1) + (xcd-r)*q) + idx;
}

// ---------------- utility ----------------
__global__ void k_zerof(float* p, int n){
  int i = blockIdx.x*256 + threadIdx.x;
  if (i < n) p[i] = 0.f;
}
__global__ void k_zeroi(int* p, int n){
  int i = blockIdx.x*256 + threadIdx.x;
  if (i < n) p[i] = 0;
}

// ---------------- CSR build ----------------
__global__ void k_hist(const int* __restrict__ dst, int E, int* deg){
  int e = blockIdx.x*256 + threadIdx.x;
  if (e < E) atomicAdd(&deg[dst[e]], 1);
}

__global__ __launch_bounds__(1024) void k_scan(int* degcur, int* __restrict__ rowptr, int n){
  __shared__ int wsum[16];
  __shared__ int carry;
  int tid = threadIdx.x, wid = tid >> 6, lane = tid & 63;
  if (tid == 0){ carry = 0; rowptr[0] = 0; }
  __syncthreads();
  for (int base = 0; base < n; base += 1024){
    int v = (base + tid < n) ? degcur[base + tid] : 0;
    int s = v;
#pragma unroll
    for (int off = 1; off < 64; off <<= 1){
      int t = __shfl_up(s, off);
      if (lane >= off) s += t;
    }
    if (lane == 63) wsum[wid] = s;
    __syncthreads();
    if (wid == 0 && lane < 16){
      int wv = wsum[lane];
#pragma unroll
      for (int off = 1; off < 16; off <<= 1){
        int t = __shfl_up(wv, off);
        if (lane >= off) wv += t;
      }
      wsum[lane] = wv;
    }
    __syncthreads();
    int incl = s + (wid ? wsum[wid-1] : 0) + carry;
    if (base + tid < n){ rowptr[base + tid + 1] = incl; degcur[base + tid] = incl - v; }
    __syncthreads();
    if (tid == 0) carry += wsum[15];
    __syncthreads();
  }
}

__global__ void k_scatter(const int* __restrict__ src, const int* __restrict__ dst,
                          int E, int* cursor, int* __restrict__ colsrc){
  int e = blockIdx.x*256 + threadIdx.x;
  if (e < E){
    int d = dst[e];
    int pos = atomicAdd(&cursor[d], 1);
    colsrc[pos] = src[e];
  }
}

__global__ void k_gstart(const int* __restrict__ batch, int N, int* __restrict__ gstart){
  int g = blockIdx.x*256 + threadIdx.x;
  if (g <= NG){
    int lo = 0, hi = N;
    while (lo < hi){
      int mid = (lo + hi) >> 1;
      if (batch[mid] < g) lo = mid + 1; else hi = mid;
    }
    gstart[g] = lo;
  }
}

// ---- weight cast+transpose: W[k][n] f32 -> Wt[n][ldt] bf16 at column offset koff ----
__global__ void k_castT(const float* __restrict__ W, unsigned short* __restrict__ Wt,
                        int K, int Nn, int ldt, int koff){
  __shared__ float sh[32][33];
  const size_t in_off  = (size_t)blockIdx.z * K * Nn;
  const size_t out_off = (size_t)blockIdx.z * Nn * ldt;
  int n0 = blockIdx.x*32, k0 = blockIdx.y*32;
  int tx = threadIdx.x, ty = threadIdx.y;   // 32 x 8
  for (int r = ty; r < 32; r += 8)
    sh[r][tx] = W[in_off + (size_t)(k0 + r)*Nn + n0 + tx];
  __syncthreads();
  for (int r = ty; r < 32; r += 8)
    Wt[out_off + (size_t)(n0 + r)*ldt + koff + k0 + tx] = f2bf(sh[tx][r]);
}

__global__ void k_bias2(const float* __restrict__ a, const float* __restrict__ b,
                        float* __restrict__ o){
  int i = threadIdx.x;
  o[i] = a[i] + b[i];
}

// ---------------- pooling + prediction heads ----------------
__global__ __launch_bounds__(320) void k_pool(const unsigned short* __restrict__ xall,
                                              const int* __restrict__ gstart,
                                              float* __restrict__ pooled){
  int g = blockIdx.x;
  int t = threadIdx.x;
  int n0 = gstart[g], n1 = gstart[g+1];
  float a0 = 0.f, a1 = 0.f;
  for (int n = n0; n < n1; ++n){
    unsigned u = ((const unsigned*)xall)[(size_t)n*(EMB/2) + t];
    a0 += bf2f((unsigned short)u); a1 += bf2f((unsigned short)(u >> 16));
  }
  *(float2*)(pooled + (size_t)g*EMB + 2*t) = make_float2(a0, a1);
}

__global__ __launch_bounds__(128) void k_pred(const float* __restrict__ pooled,
                                              const float* __restrict__ W,
                                              const float* __restrict__ b,
                                              float* __restrict__ xcat){
  int g = blockIdx.x, l = blockIdx.y, o = threadIdx.x;
  __shared__ float sh[128];
  sh[o] = pooled[(size_t)g*EMB + l*H + o];
  __syncthreads();
  const float* Wl = W + (size_t)l*H*H;
  float acc = b[l*H + o];
  for (int k = 0; k < H; ++k) acc = fmaf(sh[k], Wl[k*H + o], acc);
  xcat[(size_t)g*EMB + l*H + o] = acc;
}

// ---- bf16 MFMA GEMM, 128x128 tile, BK=64, depth-2 pipeline, RAW s_barrier ----
// ds_read frags -> s_barrier -> STAGE(t+2) -> MFMA -> counted vmcnt(4) -> s_barrier.
// No vmcnt(0) drain in the main loop (T4). 8 waves (2x4), 64x32 wave tile.
// DUAL: A rows are [A | A2] concatenated along K (each K/2 wide).
template<bool RELU, bool OUT_BF16, bool DUAL>
__global__ __launch_bounds__(512) void k_mm(
    const unsigned short* __restrict__ A, int lda,
    const unsigned short* __restrict__ A2,
    const unsigned short* __restrict__ Bt, int ldb,
    const float* __restrict__ bias,
    void* __restrict__ Cv, int ldc,
    int M, int K)
{
  __shared__ union LdsU {
    unsigned short stage[2][2][8192];   // [buf][A/B] 16 KB each => 64 KB
    unsigned short sc16[128*136];       // epilogue scratch bf16
    float          sc32[128*132];       // epilogue scratch f32
  } u;
  const int tid  = threadIdx.x;
  const int lane = tid & 63;
  const int w    = tid >> 6;            // 0..7
  const int wr   = w >> 2, wc = w & 3;  // 2x4 wave grid; wave tile 64x32

  const int nwg = gridDim.x * gridDim.y;
  const int bid = blockIdx.y * gridDim.x + blockIdx.x;
  const int wg  = xcd_swz(bid, nwg);
  const int col0 = (wg % gridDim.x) * 128;
  const int row0 = (wg / gridDim.x) * 128;
  const int KA   = DUAL ? (K >> 1) : K;

  // staging sources: wave w owns 2 KB of each 16-KB array (2 chunks of 1 KB)
  const unsigned short *sA[2], *sA2p[2], *sB[2];
  int dOff[2];
#pragma unroll
  for (int j = 0; j < 2; ++j){
    int d = w*2048 + j*1024 + lane*16;        // linear LDS byte dest
    int m = d >> 7;                           // tile row (128-B rows)
    int inner = (d & 127) ^ ((m & 7) << 4);   // inverse-swizzled byte-in-row
    int gm = row0 + m; if (gm > M-1) gm = M-1;
    sA[j]  = A + (size_t)gm*lda + (inner >> 1);
    if (DUAL) sA2p[j] = A2 + (size_t)gm*lda + (inner >> 1);
    sB[j]  = Bt + (size_t)(col0 + m)*ldb + (inner >> 1);
    dOff[j] = w*2048 + j*1024;
  }

  f32x4 acc[4][2];
#pragma unroll
  for (int i = 0; i < 4; ++i)
#pragma unroll
    for (int j = 0; j < 2; ++j)
      acc[i][j] = (f32x4){0.f, 0.f, 0.f, 0.f};

  auto STAGE = [&](int buf, int kt){          // 4 loads per wave
    int k0 = kt*64, ka = k0;
    bool second = DUAL && (k0 >= KA);
    if (second) ka = k0 - KA;
#pragma unroll
    for (int j = 0; j < 2; ++j){
      const unsigned short* s = second ? (sA2p[j] + ka) : (sA[j] + ka);
      __builtin_amdgcn_global_load_lds(
          (const __attribute__((address_space(1))) void*)s,
          (__attribute__((address_space(3))) void*)((char*)&u.stage[buf][0][0] + dOff[j]),
          16, 0, 0);
    }
#pragma unroll
    for (int j = 0; j < 2; ++j)
      __builtin_amdgcn_global_load_lds(
          (const __attribute__((address_space(1))) void*)(sB[j] + k0),
          (__attribute__((address_space(3))) void*)((char*)&u.stage[buf][1][0] + dOff[j]),
          16, 0, 0);
  };

  const int NT = K / 64;    // >= 4 for all uses
  STAGE(0, 0);
  STAGE(1, 1);
  asm volatile("s_waitcnt vmcnt(4)" ::: "memory");   // tile 0 landed, tile 1 flying
  asm volatile("s_barrier" ::: "memory");

  for (int t = 0; t < NT; ++t){
    const char* Ab = (const char*)&u.stage[t & 1][0][0];
    const char* Bb = (const char*)&u.stage[t & 1][1][0];
    // ---- ds_read all fragments for this K-tile
    bf16x8 af[2][4], bq[2][2];
#pragma unroll
    for (int kk = 0; kk < 2; ++kk){
      const int kb = kk*64 + ((lane >> 4) << 4);
#pragma unroll
      for (int i = 0; i < 4; ++i){
        int row = wr*64 + i*16 + (lane & 15);
        af[kk][i] = *(const bf16x8*)(Ab + ((row*128 + kb) ^ ((row & 7) << 4)));
      }
#pragma unroll
      for (int j = 0; j < 2; ++j){
        int col = wc*32 + j*16 + (lane & 15);
        bq[kk][j] = *(const bf16x8*)(Bb + ((col*128 + kb) ^ ((col & 7) << 4)));
      }
    }
    // ---- reads issued by all waves -> safe to overwrite this buffer
    if (t + 2 < NT){
      asm volatile("s_barrier" ::: "memory");
      STAGE(t & 1, t + 2);
    }
    // ---- MFMA (compiler inserts lgkmcnt waits for af/bq)
#pragma unroll
    for (int kk = 0; kk < 2; ++kk)
#pragma unroll
      for (int i = 0; i < 4; ++i)
#pragma unroll
        for (int j = 0; j < 2; ++j)
          acc[i][j] = __builtin_amdgcn_mfma_f32_16x16x32_bf16(af[kk][i], bq[kk][j], acc[i][j], 0, 0, 0);
    // ---- make tile t+1 readable (counted; never 0 until tail)
    if (t + 1 < NT){
      if (t + 2 < NT) asm volatile("s_waitcnt vmcnt(4)" ::: "memory");
      else            asm volatile("s_waitcnt vmcnt(0)" ::: "memory");
      asm volatile("s_barrier" ::: "memory");
    }
  }

  // ---- epilogue: transpose via LDS, coalesced stream-out ----
  __syncthreads();   // full drain; staging buffers now dead
  if (OUT_BF16){
#pragma unroll
    for (int j = 0; j < 2; ++j){
      int cl = wc*32 + j*16 + (lane & 15);
      float bs = bias[col0 + cl];
#pragma unroll
      for (int i = 0; i < 4; ++i){
        int rb = wr*64 + i*16 + ((lane >> 4) << 2);
#pragma unroll
        for (int r = 0; r < 4; ++r){
          float v = acc[i][j][r] + bs;
          if (RELU) v = fmaxf(v, 0.f);
          u.sc16[(rb + r)*136 + cl] = f2bf(v);
        }
      }
    }
    __syncthreads();
    unsigned short* Cb = (unsigned short*)Cv;
    for (int idx = tid; idx < 128*16; idx += 512){
      int rr = idx >> 4, seg = idx & 15;
      int grow = row0 + rr;
      if (grow < M){
        uint4 vv = *(const uint4*)&u.sc16[rr*136 + seg*8];
        *(uint4*)(Cb + (size_t)grow*ldc + col0 + seg*8) = vv;
      }
    }
  } else {
#pragma unroll
    for (int j = 0; j < 2; ++j){
      int cl = wc*32 + j*16 + (lane & 15);
      float bs = bias[col0 + cl];
#pragma unroll
      for (int i = 0; i < 4; ++i){
        int rb = wr*64 + i*16 + ((lane >> 4) << 2);
#pragma unroll
        for (int r = 0; r < 4; ++r){
          float v = acc[i][j][r] + bs;
          if (RELU) v = fmaxf(v, 0.f);
          u.sc32[(rb + r)*132 + cl] = v;
        }
      }
    }
    __syncthreads();
    float* Cf = (float*)Cv;
    for (int idx = tid; idx < 128*32; idx += 512){
      int rr = idx >> 5, seg = idx & 31;
      int grow = row0 + rr;
      if (grow < M){
        float4 vv = *(const float4*)&u.sc32[rr*132 + seg*4];
        *(float4*)(Cf + (size_t)grow*ldc + col0 + seg*4) = vv;
      }
    }
  }
}

// ------- fused GIN-aggregate + conv GEMM1 + stats: ub = agg(h) @ W1 + b1 -------
template<bool IN_BF16>
__global__ __launch_bounds__(512) void k_mmca(
    const void* __restrict__ hin, int ldh,
    const int* __restrict__ rowptr, const int* __restrict__ colsrc,
    const float* __restrict__ epsp,
    const unsigned short* __restrict__ Bt,    // [128][128] bf16, n-major
    const float* __restrict__ bias,
    unsigned short* __restrict__ C, int ldc,
    float* __restrict__ sums, float* __restrict__ sumsq,
    int M)
{
  __shared__ unsigned short shm[2*128*128];   // As | Bs (32 KB each); epilogue reuse
  unsigned short* As = shm;
  unsigned short* Bs = shm + 16384;
  const int tid  = threadIdx.x;
  const int lane = tid & 63;
  const int w    = tid >> 6;
  const int wr   = w >> 2, wc = w & 3;

  const int wg   = xcd_swz(blockIdx.x, gridDim.x);
  const int row0 = wg * 128;

  // issue B staging first (pre-swizzled source, linear dest)
#pragma unroll
  for (int j = 0; j < 4; ++j){
    int d = w*4096 + j*1024 + lane*16;
    int m = d >> 8;
    int inner = (d & 255) ^ ((m & 15) << 4);
    __builtin_amdgcn_global_load_lds(
        (const __attribute__((address_space(1))) void*)(Bt + (size_t)m*H + (inner >> 1)),
        (__attribute__((address_space(3))) void*)((char*)Bs + w*4096 + j*1024),
        16, 0, 0);
  }

  // gather A: thread handles row r = tid>>2, 32 cols at c0 = (tid&3)*32
  {
    int r  = tid >> 2;
    int c0 = (tid & 3) << 5;
    int node = row0 + r; if (node > M-1) node = M-1;
    float ep = 1.0f + *epsp;
    float a[32];
    if (IN_BF16){
      const unsigned short* src = (const unsigned short*)hin + (size_t)node*ldh + c0;
#pragma unroll
      for (int q = 0; q < 4; ++q){
        uint2 v = *(const uint2*)(src + q*8);
        a[q*8+0] = ep*bf2f((unsigned short)v.x);  a[q*8+1] = ep*bf2f((unsigned short)(v.x>>16));
        uint2 v2 = *(const uint2*)(src + q*8 + 4);
        a[q*8+2] = ep*bf2f((unsigned short)v.y);  a[q*8+3] = ep*bf2f((unsigned short)(v.y>>16));
        a[q*8+4] = ep*bf2f((unsigned short)v2.x); a[q*8+5] = ep*bf2f((unsigned short)(v2.x>>16));
        a[q*8+6] = ep*bf2f((unsigned short)v2.y); a[q*8+7] = ep*bf2f((unsigned short)(v2.y>>16));
      }
    } else {
      const float* src = (const float*)hin + (size_t)node*ldh + c0;
#pragma unroll
      for (int q = 0; q < 32; q += 4){
        float4 f = *(const float4*)(src + q);
        a[q] = ep*f.x; a[q+1] = ep*f.y; a[q+2] = ep*f.z; a[q+3] = ep*f.w;
      }
    }
    int e = rowptr[node], e1 = rowptr[node+1];
    for (; e < e1; ++e){
      int s = colsrc[e];
      if (IN_BF16){
        const unsigned short* p = (const unsigned short*)hin + (size_t)s*ldh + c0;
        uint4 v0 = *(const uint4*)(p);
        uint4 v1 = *(const uint4*)(p + 8);
        uint4 v2 = *(const uint4*)(p + 16);
        uint4 v3 = *(const uint4*)(p + 24);
        const unsigned* uu[4] = {(const unsigned*)&v0, (const unsigned*)&v1,
                                 (const unsigned*)&v2, (const unsigned*)&v3};
#pragma unroll
        for (int q = 0; q < 4; ++q)
#pragma unroll
          for (int k = 0; k < 4; ++k){
            unsigned x = uu[q][k];
            a[q*8 + 2*k]     += bf2f((unsigned short)x);
            a[q*8 + 2*k + 1] += bf2f((unsigned short)(x >> 16));
          }
      } else {
        const float* p = (const float*)hin + (size_t)s*ldh + c0;
#pragma unroll
        for (int q = 0; q < 32; q += 4){
          float4 f = *(const float4*)(p + q);
          a[q] += f.x; a[q+1] += f.y; a[q+2] += f.z; a[q+3] += f.w;
        }
      }
    }
    // write 32 bf16 (64 B = 4 swizzled 16-B chunks) into As
#pragma unroll
    for (int q = 0; q < 4; ++q){
      unsigned pk[4];
#pragma unroll
      for (int k = 0; k < 4; ++k)
        pk[k] = (unsigned)f2bf(a[q*8 + 2*k]) | ((unsigned)f2bf(a[q*8 + 2*k + 1]) << 16);
      int byte = (r*256 + (tid & 3)*64 + q*16) ^ ((r & 15) << 4);
      *(uint4*)((char*)As + byte) = *(uint4*)pk;
    }
  }

  asm volatile("s_waitcnt vmcnt(0)" ::: "memory");
  __syncthreads();

  f32x4 acc[4][2];
#pragma unroll
  for (int i = 0; i < 4; ++i)
#pragma unroll
    for (int j = 0; j < 2; ++j)
      acc[i][j] = (f32x4){0.f, 0.f, 0.f, 0.f};

#pragma unroll
  for (int kk = 0; kk < 4; ++kk){
    const int kb = kk*64 + ((lane >> 4) << 4);
    bf16x8 af[4], bfr[2];
#pragma unroll
    for (int i = 0; i < 4; ++i){
      int row = wr*64 + i*16 + (lane & 15);
      af[i] = *(const bf16x8*)((const char*)As + ((row*256 + kb) ^ ((row & 15) << 4)));
    }
#pragma unroll
    for (int j = 0; j < 2; ++j){
      int col = wc*32 + j*16 + (lane & 15);
      bfr[j] = *(const bf16x8*)((const char*)Bs + ((col*256 + kb) ^ ((col & 15) << 4)));
    }
#pragma unroll
    for (int i = 0; i < 4; ++i)
#pragma unroll
      for (int j = 0; j < 2; ++j)
        acc[i][j] = __builtin_amdgcn_mfma_f32_16x16x32_bf16(af[i], bfr[j], acc[i][j], 0, 0, 0);
  }

  // fused column stats
#pragma unroll
  for (int j = 0; j < 2; ++j){
    int col = wc*32 + j*16 + (lane & 15);
    float bs = bias[col];
    float s = 0.f, q = 0.f;
#pragma unroll
    for (int i = 0; i < 4; ++i){
      int rb = row0 + wr*64 + i*16 + ((lane >> 4) << 2);
#pragma unroll
      for (int r = 0; r < 4; ++r){
        if (rb + r < M){
          float v = acc[i][j][r] + bs;
          s += v; q += v*v;
        }
      }
    }
    s += __shfl_xor(s, 16); q += __shfl_xor(q, 16);
    s += __shfl_xor(s, 32); q += __shfl_xor(q, 32);
    if (lane < 16){
      atomicAdd(&sums[col], s);
      atomicAdd(&sumsq[col], q);
    }
  }

  // epilogue: transpose via LDS (staging dead), coalesced 16-B stores
  __syncthreads();
#pragma unroll
  for (int j = 0; j < 2; ++j){
    int cl = wc*32 + j*16 + (lane & 15);
    float bs = bias[cl];
#pragma unroll
    for (int i = 0; i < 4; ++i){
      int rb = wr*64 + i*16 + ((lane >> 4) << 2);
#pragma unroll
      for (int r = 0; r < 4; ++r)
        shm[(rb + r)*136 + cl] = f2bf(acc[i][j][r] + bs);
    }
  }
  __syncthreads();
  for (int idx = tid; idx < 128*16; idx += 512){
    int rr = idx >> 4, seg = idx & 15;
    int grow = row0 + rr;
    if (grow < M){
      uint4 vv = *(const uint4*)&shm[rr*136 + seg*8];
      *(uint4*)(C + (size_t)grow*ldc + seg*8) = vv;
    }
  }
}

// ------- conv GEMM2 with inline BN1 finalize on A + stats: tb = relu(bn1(ub)) @ W2 + b2 -------
__global__ __launch_bounds__(512) void k_mmc2(
    const unsigned short* __restrict__ A,     // [M][128] bf16 (pre-BN1)
    const unsigned short* __restrict__ Bt,    // [128][128] bf16, n-major
    const float* __restrict__ bias,           // [128]
    const float* __restrict__ statin,         // BN1 slot: sums[128]|sumsq[128]
    const float* __restrict__ g1, const float* __restrict__ be1,
    float invn,
    unsigned short* __restrict__ C, int ldc,
    float* __restrict__ sums, float* __restrict__ sumsq,   // BN2 slot
    int M)
{
  __shared__ unsigned short shm[2*128*128];
  __shared__ float bnsc[128], bnsf[128];
  unsigned short* As = shm;
  unsigned short* Bs = shm + 16384;
  const int tid  = threadIdx.x;
  const int lane = tid & 63;
  const int w    = tid >> 6;
  const int wr   = w >> 2, wc = w & 3;

  const int wg   = xcd_swz(blockIdx.x, gridDim.x);
  const int row0 = wg * 128;

#pragma unroll
  for (int j = 0; j < 4; ++j){
    int d = w*4096 + j*1024 + lane*16;
    int m = d >> 8;
    int inner = (d & 255) ^ ((m & 15) << 4);
    int gm = row0 + m; if (gm > M-1) gm = M-1;
    __builtin_amdgcn_global_load_lds(
        (const __attribute__((address_space(1))) void*)(A + (size_t)gm*H + (inner >> 1)),
        (__attribute__((address_space(3))) void*)((char*)As + w*4096 + j*1024),
        16, 0, 0);
    __builtin_amdgcn_global_load_lds(
        (const __attribute__((address_space(1))) void*)(Bt + (size_t)m*H + (inner >> 1)),
        (__attribute__((address_space(3))) void*)((char*)Bs + w*4096 + j*1024),
        16, 0, 0);
  }

  // inline BN1 finalize (overlaps with staging)
  if (tid < 128){
    float m = statin[tid]*invn;
    float v = statin[128 + tid]*invn - m*m;
    float inv = rsqrtf(v + BN_EPS);
    float sc = g1[tid]*inv;
    bnsc[tid] = sc;
    bnsf[tid] = be1[tid] - m*sc;
  }

  asm volatile("s_waitcnt vmcnt(0)" ::: "memory");
  __syncthreads();

  f32x4 acc[4][2];
#pragma unroll
  for (int i = 0; i < 4; ++i)
#pragma unroll
    for (int j = 0; j < 2; ++j)
      acc[i][j] = (f32x4){0.f, 0.f, 0.f, 0.f};

#pragma unroll
  for (int kk = 0; kk < 4; ++kk){
    const int kb = kk*64 + ((lane >> 4) << 4);
    bf16x8 af[4], bfr[2];
#pragma unroll
    for (int i = 0; i < 4; ++i){
      int row = wr*64 + i*16 + (lane & 15);
      af[i] = *(const bf16x8*)((const char*)As + ((row*256 + kb) ^ ((row & 15) << 4)));
    }
#pragma unroll
    for (int j = 0; j < 2; ++j){
      int col = wc*32 + j*16 + (lane & 15);
      bfr[j] = *(const bf16x8*)((const char*)Bs + ((col*256 + kb) ^ ((col & 15) << 4)));
    }
    {
      int k8 = kk*32 + ((lane >> 4) << 3);
      float4 s0 = *(const float4*)(&bnsc[k8]), s1 = *(const float4*)(&bnsc[k8 + 4]);
      float4 f0 = *(const float4*)(&bnsf[k8]), f1 = *(const float4*)(&bnsf[k8 + 4]);
      float sc[8] = {s0.x,s0.y,s0.z,s0.w,s1.x,s1.y,s1.z,s1.w};
      float sf[8] = {f0.x,f0.y,f0.z,f0.w,f1.x,f1.y,f1.z,f1.w};
#pragma unroll
      for (int i = 0; i < 4; ++i){
        bf16x8 aa = af[i], o;
#pragma unroll
        for (int jj = 0; jj < 8; ++jj){
          float v = fmaxf(fmaf(sc[jj], bf2f((unsigned short)aa[jj]), sf[jj]), 0.f);
          o[jj] = (short)f2bf(v);
        }
        af[i] = o;
      }
    }
#pragma unroll
    for (int i = 0; i < 4; ++i)
#pragma unroll
      for (int j = 0; j < 2; ++j)
        acc[i][j] = __builtin_amdgcn_mfma_f32_16x16x32_bf16(af[i], bfr[j], acc[i][j], 0, 0, 0);
  }

#pragma unroll
  for (int j = 0; j < 2; ++j){
    int col = wc*32 + j*16 + (lane & 15);
    float bs = bias[col];
    float s = 0.f, q = 0.f;
#pragma unroll
    for (int i = 0; i < 4; ++i){
      int rb = row0 + wr*64 + i*16 + ((lane >> 4) << 2);
#pragma unroll
      for (int r = 0; r < 4; ++r){
        if (rb + r < M){
          float v = acc[i][j][r] + bs;
          s += v; q += v*v;
        }
      }
    }
    s += __shfl_xor(s, 16); q += __shfl_xor(q, 16);
    s += __shfl_xor(s, 32); q += __shfl_xor(q, 32);
    if (lane < 16){
      atomicAdd(&sums[col], s);
      atomicAdd(&sumsq[col], q);
    }
  }

  __syncthreads();
#pragma unroll
  for (int j = 0; j < 2; ++j){
    int cl = wc*32 + j*16 + (lane & 15);
    float bs = bias[cl];
#pragma unroll
    for (int i = 0; i < 4; ++i){
      int rb = wr*64 + i*16 + ((lane >> 4) << 2);
#pragma unroll
      for (int r = 0; r < 4; ++r)
        shm[(rb + r)*136 + cl] = f2bf(acc[i][j][r] + bs);
    }
  }
  __syncthreads();
  for (int idx = tid; idx < 128*16; idx += 512){
    int rr = idx >> 4, seg = idx & 15;
    int grow = row0 + rr;
    if (grow < M){
      uint4 vv = *(const uint4*)&shm[rr*136 + seg*8];
      *(uint4*)(C + (size_t)grow*ldc + seg*8) = vv;
    }
  }
}

// ---- BN2 apply with inline finalize: out = bf16(relu(sc*U+sf)) ----
__global__ __launch_bounds__(256) void k_bnapply(const unsigned short* __restrict__ U,
                                                 const float* __restrict__ statp,
                                                 const float* __restrict__ g,
                                                 const float* __restrict__ b,
                                                 float invn,
                                                 unsigned short* __restrict__ out,
                                                 int ldo, int n){
  int i = blockIdx.x*256 + threadIdx.x;
  int total = n * (H/4);
  if (i < total){
    int r = i >> 5;
    int c4 = (i & 31) << 2;
    float4 sm = *(const float4*)(statp + c4);
    float4 sq = *(const float4*)(statp + 128 + c4);
    float4 gg = *(const float4*)(g + c4);
    float4 bb = *(const float4*)(b + c4);
    float m0 = sm.x*invn, m1 = sm.y*invn, m2 = sm.z*invn, m3 = sm.w*invn;
    float s0 = gg.x*rsqrtf(sq.x*invn - m0*m0 + BN_EPS);
    float s1 = gg.y*rsqrtf(sq.y*invn - m1*m1 + BN_EPS);
    float s2 = gg.z*rsqrtf(sq.z*invn - m2*m2 + BN_EPS);
    float s3 = gg.w*rsqrtf(sq.w*invn - m3*m3 + BN_EPS);
    float f0 = bb.x - m0*s0, f1 = bb.y - m1*s1, f2 = bb.z - m2*s2, f3 = bb.w - m3*s3;
    uint2 up = *(const uint2*)(U + (size_t)r*H + c4);
    float a = fmaxf(fmaf(s0, bf2f((unsigned short)up.x),       f0), 0.f);
    float c = fmaxf(fmaf(s1, bf2f((unsigned short)(up.x>>16)), f1), 0.f);
    float d = fmaxf(fmaf(s2, bf2f((unsigned short)up.y),       f2), 0.f);
    float e = fmaxf(fmaf(s3, bf2f((unsigned short)(up.y>>16)), f3), 0.f);
    uint2 o;
    o.x = (unsigned)f2bf(a) | ((unsigned)f2bf(c) << 16);
    o.y = (unsigned)f2bf(d) | ((unsigned)f2bf(e) << 16);
    *(uint2*)(out + (size_t)r*ldo + c4) = o;
  }
}

// ---------------- f32 GEMM 64x64 (graph FF, M=512) ----------------
template<bool RELU, bool ADD_D>
__global__ __launch_bounds__(256) void k_gemm64(
    const float* __restrict__ A, int lda,
    const float* __restrict__ B, int ldb,
    const float* __restrict__ bias,
    const float* D, int ldd,
    float* C, int ldc,
    int M, int N, int K)
{
  __shared__ float As[32][68];
  __shared__ float Bs[32][64];
  const int tid  = threadIdx.x;
  const int tx   = tid & 15;
  const int ty   = tid >> 4;
  const int row0 = blockIdx.x * 64;
  const int col0 = blockIdx.y * 64;
  const int am = tid >> 3;
  const int ak = (tid & 7) << 2;
  const int bk = tid >> 4;
  const int bn = (tid & 15) << 2;
  float acc[4][4] = {};

  for (int k0 = 0; k0 < K; k0 += 32){
#pragma unroll
    for (int h = 0; h < 2; ++h){
      int m  = am + h*32;
      int gr = row0 + m;
      float4 v = make_float4(0.f, 0.f, 0.f, 0.f);
      if (gr < M) v = *(const float4*)(A + (size_t)gr*lda + k0 + ak);
      As[ak+0][m]=v.x; As[ak+1][m]=v.y; As[ak+2][m]=v.z; As[ak+3][m]=v.w;
    }
#pragma unroll
    for (int h = 0; h < 2; ++h){
      int kk = bk + h*16;
      *(float4*)(&Bs[kk][bn]) = *(const float4*)(B + (size_t)(k0+kk)*ldb + col0 + bn);
    }
    __syncthreads();
#pragma unroll 8
    for (int k = 0; k < 32; ++k){
      float4 a = *(const float4*)(&As[k][ty<<2]);
      float4 b = *(const float4*)(&Bs[k][tx<<2]);
      float av[4] = {a.x,a.y,a.z,a.w};
      float bv[4] = {b.x,b.y,b.z,b.w};
#pragma unroll
      for (int i = 0; i < 4; ++i)
#pragma unroll
        for (int j = 0; j < 4; ++j)
          acc[i][j] = fmaf(av[i], bv[j], acc[i][j]);
    }
    __syncthreads();
  }

  const int col = col0 + (tx<<2);
  float4 bv = *(const float4*)(bias + col);
#pragma unroll
  for (int i = 0; i < 4; ++i){
    int row = row0 + (ty<<2) + i;
    if (row < M){
      float r[4] = {acc[i][0]+bv.x, acc[i][1]+bv.y, acc[i][2]+bv.z, acc[i][3]+bv.w};
      if (RELU){
#pragma unroll
        for (int j = 0; j < 4; ++j) r[j] = fmaxf(r[j], 0.f);
      }
      if (ADD_D){
        float4 d = *(const float4*)(D + (size_t)row*ldd + col);
        r[0]+=d.x; r[1]+=d.y; r[2]+=d.z; r[3]+=d.w;
      }
      *(float4*)(C + (size_t)row*ldc + col) = make_float4(r[0],r[1],r[2],r[3]);
    }
  }
}

// ---------------- host ----------------
extern "C" void kernel_launch(void* const* d_in, const int* in_sizes, int n_in,
                              void* d_out, int out_size, void* d_ws, size_t ws_size,
                              hipStream_t stream) {
  const float* x        = (const float*)d_in[0];
  const int*   ei       = (const int*)d_in[1];
  const int*   batch    = (const int*)d_in[2];
  const float* conv_W1  = (const float*)d_in[3];
  const float* conv_b1  = (const float*)d_in[4];
  const float* conv_g1  = (const float*)d_in[5];
  const float* conv_be1 = (const float*)d_in[6];
  const float* conv_W2  = (const float*)d_in[7];
  const float* conv_b2  = (const float*)d_in[8];
  const float* epsv     = (const float*)d_in[9];
  const float* bn_g     = (const float*)d_in[10];
  const float* bn_b     = (const float*)d_in[11];
  const float* pred_W   = (const float*)d_in[12];
  const float* pred_b   = (const float*)d_in[13];
  const float* gW       = (const float*)d_in[14];
  const float* gb       = (const float*)d_in[15];
  const float* gsW      = (const float*)d_in[16];
  const float* gsb      = (const float*)d_in[17];
  const float* lW       = (const float*)d_in[18];
  const float* lb       = (const float*)d_in[19];
  const float* lsW      = (const float*)d_in[20];
  const float* lsb      = (const float*)d_in[21];

  const int N = in_sizes[0] / H;
  const int E = in_sizes[1] / 2;
  const int* srcI = ei;
  const int* dstI = ei + E;

  float* out = (float*)d_out;
  float* GE = out;                              // [NG][EMB]
  float* NE = out + (size_t)NG*EMB;             // [N][EMB] f32
  float* XC = NE + (size_t)N*EMB;               // [NG][EMB]

  // ---- workspace layout ----
  unsigned short* xall = (unsigned short*)d_ws;             // [N][EMB] bf16
  unsigned short* h1   = xall + (size_t)N*EMB;              // [N][EMB] bf16
  unsigned short* h2   = h1 + (size_t)N*EMB;                // [N][EMB] bf16
  unsigned short* ub   = h1;                                // [N][H] (alias, conv loop)
  unsigned short* tb   = h1 + (size_t)N*H;                  // [N][H]

  float* pooled  = (float*)(h2 + (size_t)N*EMB);            // [NG][EMB]
  float* gtmp1   = pooled + (size_t)NG*EMB;
  float* gtmp2   = gtmp1 + (size_t)NG*EMB;
  float* slots   = gtmp2 + (size_t)NG*EMB;                  // [10][256] stat slots
  float* biasNE  = slots + 2560;                            // [640]
  unsigned short* W1t   = (unsigned short*)(biasNE + EMB);  // [L][H][H]
  unsigned short* W2t   = W1t + (size_t)LNUM*H*H;
  unsigned short* lWt01 = W2t + (size_t)LNUM*H*H;           // [2][EMB][EMB]
  unsigned short* Wcat  = lWt01 + (size_t)2*EMB*EMB;        // [EMB][2*EMB]
  int* rowptr = (int*)(Wcat + (size_t)2*EMB*EMB);           // [N+1]
  int* cursor = rowptr + (N + 1);                           // [N]
  int* colsrc = cursor + N;                                 // [E]
  int* gstart = colsrc + E;                                 // [NG+1]

  // stat slots must be zero every call
  k_zerof<<<10, 256, 0, stream>>>(slots, 2560);

  // CSR build
  k_zeroi<<<(N+255)/256, 256, 0, stream>>>(cursor, N);
  k_hist<<<(E+255)/256, 256, 0, stream>>>(dstI, E, cursor);
  k_scan<<<1, 1024, 0, stream>>>(cursor, rowptr, N);
  k_scatter<<<(E+255)/256, 256, 0, stream>>>(srcI, dstI, E, cursor, colsrc);
  k_gstart<<<(NG+256)/256, 256, 0, stream>>>(batch, N, gstart);

  // weights -> bf16 transposed [n][k]
  const dim3 tb32(32, 8);
  k_castT<<<dim3(H/32, H/32, LNUM), tb32, 0, stream>>>(conv_W1, W1t, H, H, H, 0);
  k_castT<<<dim3(H/32, H/32, LNUM), tb32, 0, stream>>>(conv_W2, W2t, H, H, H, 0);
  k_castT<<<dim3(EMB/32, EMB/32, 2), tb32, 0, stream>>>(lW, lWt01, EMB, EMB, EMB, 0);
  k_castT<<<dim3(EMB/32, EMB/32, 1), tb32, 0, stream>>>(lW + (size_t)2*EMB*EMB, Wcat,
                                                        EMB, EMB, 2*EMB, 0);
  k_castT<<<dim3(EMB/32, EMB/32, 1), tb32, 0, stream>>>(lsW, Wcat, EMB, EMB, 2*EMB, EMB);
  k_bias2<<<1, EMB, 0, stream>>>(lb + (size_t)2*EMB, lsb, biasNE);

  const float invn = 1.0f / (float)N;
  const int nrow = (N + 127)/128;               // 391

  for (int l = 0; l < LNUM; ++l){
    float* slot1 = slots + (size_t)l*512;       // BN1: sums|sumsq
    float* slot2 = slot1 + 256;                 // BN2

    // ub = agg(h) @ W1 + b1  (fused gather; bf16 out + stats)
    if (l == 0)
      k_mmca<false><<<nrow, 512, 0, stream>>>(
          x, H, rowptr, colsrc, epsv, W1t, conv_b1,
          ub, H, slot1, slot1 + 128, N);
    else
      k_mmca<true><<<nrow, 512, 0, stream>>>(
          xall + (size_t)(l-1)*H, EMB, rowptr, colsrc, epsv + l,
          W1t + (size_t)l*H*H, conv_b1 + l*H,
          ub, H, slot1, slot1 + 128, N);

    // tb = relu(bn1(ub)) @ W2 + b2  (inline BN1 finalize; bf16 out + stats)
    k_mmc2<<<nrow, 512, 0, stream>>>(
        ub, W2t + (size_t)l*H*H, conv_b2 + l*H,
        slot1, conv_g1 + l*H, conv_be1 + l*H, invn,
        tb, H, slot2, slot2 + 128, N);

    // xall[:,l*H:] = relu(bn2(tb))  (inline BN2 finalize)
    k_bnapply<<<(N*32 + 255)/256, 256, 0, stream>>>(
        tb, slot2, bn_g + l*H, bn_b + l*H, invn,
        xall + (size_t)l*H, EMB, N);
  }

  // pooling + per-layer prediction heads -> xcat
  k_pool<<<NG, 320, 0, stream>>>(xall, gstart, pooled);
  k_pred<<<dim3(NG, LNUM), 128, 0, stream>>>(pooled, pred_W, pred_b, XC);

  // graph FF (f32, M=512): GE = relu-chain(XC) + XC @ gsW + gsb
  const dim3 gg((NG + 63)/64, EMB/64);
  k_gemm64<false,false><<<gg, 256, 0, stream>>>(XC, EMB, gsW, EMB, gsb,
                                                nullptr, 0, GE, EMB, NG, EMB, EMB);
  k_gemm64<true,false><<<gg, 256, 0, stream>>>(XC, EMB, gW, EMB, gb,
                                               nullptr, 0, gtmp1, EMB, NG, EMB, EMB);
  k_gemm64<true,false><<<gg, 256, 0, stream>>>(gtmp1, EMB, gW + (size_t)EMB*EMB, EMB, gb + EMB,
                                               nullptr, 0, gtmp2, EMB, NG, EMB, EMB);
  k_gemm64<true,true><<<gg, 256, 0, stream>>>(gtmp2, EMB, gW + (size_t)2*EMB*EMB, EMB, gb + 2*EMB,
                                              GE, EMB, GE, EMB, NG, EMB, EMB);

  // node FF (bf16 MFMA, 128x128 tile, depth-2 raw-barrier pipeline, XCD swizzle):
  const dim3 gn(EMB/128, nrow);                 // (5, 391)
  // h1 = relu(xall @ lW0 + lb0)
  k_mm<true,true,false><<<gn, 512, 0, stream>>>(
      xall, EMB, nullptr, lWt01, EMB, lb, h1, EMB, N, EMB);
  // h2 = relu(h1 @ lW1 + lb1)
  k_mm<true,true,false><<<gn, 512, 0, stream>>>(
      h1, EMB, nullptr, lWt01 + (size_t)EMB*EMB, EMB, lb + EMB, h2, EMB, N, EMB);
  // NE = [h2 | xall] @ [lW2 ; lsW] + (lb2 + lsb)   (dual-A, K=1280, f32 out)
  k_mm<false,false,true><<<gn, 512, 0, stream>>>(
      h2, EMB, xall, Wcat, 2*EMB, biasNE, NE, EMB, N, 2*EMB);
}